// Round 13
// baseline (2311.909 us; speedup 1.0000x reference)
//
#include <hip/hip_runtime.h>
#include <hip/hip_bf16.h>

#define T_DIM 256
#define B_DIM 256
#define E_DIM 256
#define H_DIM 512
#define V_DIM 50257
#define BH    (B_DIM * H_DIM)          // elems per h slot
#define RING  16                       // h ring slots (4 MB, MALL-resident)
#define PRE_AHEAD 5                    // at step t, arm slot of h_{t+5}
#define SENT  0x7F7F7F7Fu              // bf16 |h|<=1 can never be 0x7F7F

typedef __attribute__((ext_vector_type(8))) short short8;
typedef __attribute__((ext_vector_type(4))) float f32x4;
typedef __attribute__((ext_vector_type(4))) unsigned int uint4v;
typedef __attribute__((ext_vector_type(2))) unsigned int uint2v;

#define MFMA __builtin_amdgcn_mfma_f32_16x16x32_bf16

__device__ __forceinline__ unsigned short f2bf(float f) {   // staging only
    union { float f; unsigned u; } v; v.f = f;
    unsigned r = v.u + 0x7FFFu + ((v.u >> 16) & 1u);
    return (unsigned short)(r >> 16);
}
// Loop-path cvt: compiler fuses pairs into v_cvt_pk_bf16_f32 (m240).
__device__ __forceinline__ short cvt_bf(float f) {
    __hip_bfloat16 h = __float2bfloat16(f);
    return *reinterpret_cast<short*>(&h);
}
__device__ __forceinline__ float sigmoidf_(float x) {
    return 1.0f / (1.0f + __expf(-x));
}
__device__ __forceinline__ float tanhf_(float x) {
    float xc = fminf(fmaxf(x, -15.0f), 15.0f);
    float e = __expf(2.0f * xc);
    return (e - 1.0f) / (e + 1.0f);
}

// All h traffic via MALL (sc0 sc1): placement-independent; data carries its
// own readiness (sentinel); producers wait-free -> deadlock impossible.
// Loads return in-flight; consume after vmcnt + sched_barrier(0) (rule 18).
__device__ __forceinline__ short8 load16_mall(const unsigned short* p) {
    short8 r;
    asm volatile("global_load_dwordx4 %0, %1, off sc0 sc1"
                 : "=v"(r) : "v"(p) : "memory");
    return r;
}
__device__ __forceinline__ void store8_mall(unsigned short* p, uint2v v) {
    asm volatile("global_store_dwordx2 %0, %1, off sc0 sc1"
                 :: "v"(p), "v"(v) : "memory");
}
__device__ __forceinline__ bool frag_ready(short8 v) {
    union { short8 s; uint4v u; } c; c.s = v;
    return (c.u[0] != SENT) & (c.u[1] != SENT) & (c.u[2] != SENT) & (c.u[3] != SENT);
}

// ---------------- LSTM persistent kernel ----------------
// 512 blocks x 128 thr -> 2 blocks/CU (48 KiB LDS each), 4 waves/CU: all
// SIMDs busy, co-resident blocks in DIFFERENT batch groups (bijective
// swizzle) so their stall phases decorrelate.
// Roles: bg (8 groups x 32 rows), hg (64 groups x 8 hidden cols).
// Per wave: 16 rows, 2 gate tiles (t0 = gates i|j, t1 = f|o), 24 kt -> 48
// MFMA/step. Lane owns {2 gates x 4 hcols}; the other 2 gates come from
// lane^32 via one shfl_xor. Lanes<32 store 8B packed h (dword-atomic).
// h ring: 16 MALL slots, write-once/step, sentinel-armed 5 ahead (skew<=1
// within a bg by the data dependency -> reuse distance 11 is safe).
__global__ void __launch_bounds__(128, 1)
lstm_persist(const float* __restrict__ x,
             const float* __restrict__ wk,
             const float* __restrict__ bias,
             unsigned short* __restrict__ hbuf)   // [RING][B][H] bf16
{
    extern __shared__ unsigned short lds_w[];     // [48 frag][64 lane][8]
    const int tid = threadIdx.x;
    const int blk = blockIdx.x;
    const int b8  = blk >> 8;                     // 0..1
    const int bg  = (blk & 7) ^ b8;               // bijective: CU-mates differ
    const int hg  = ((blk >> 3) & 31) | (b8 << 5);
    const int bb  = bg * 32;
    const int hh  = hg * 8;

    // ---- preload weights into LDS as W^T fragments (once) ----
    // frag f = kt*2 + n; lane l (c16=l&15, lkk=l>>4); elem j:
    //   gate = n*2 + (c16>>3), hcol = c16&7, k = kt*32 + lkk*8 + j
    for (int f = 0; f < 48; ++f) {
        const int kt = f >> 1, n = f & 1;
        for (int idx = tid; idx < 512; idx += 128) {
            const int l   = idx & 63;
            const int j   = idx >> 6;
            const int c16 = l & 15;
            const int k   = kt * 32 + (l >> 4) * 8 + j;
            const int col = (n * 2 + (c16 >> 3)) * 512 + hh + (c16 & 7);
            lds_w[(f * 64 + l) * 8 + j] = f2bf(wk[(size_t)k * 2048 + col]);
        }
    }
    __syncthreads();

    const int w    = tid >> 6;        // wave: batch rows [bb+w*16, +16)
    const int lane = tid & 63;
    const int lc   = lane & 15;
    const int lk   = lane >> 4;
    const int hb4  = (lk & 1) * 4;    // lane's hcol base (0 or 4)
    const bool glo = (lane & 32) == 0;  // owns gates {i,f}; else {j,o}

    // biases for this lane's 4 hcols, all 4 gates
    const f32x4 bi  = *(const f32x4*)(bias + 0 * 512 + hh + hb4);
    const f32x4 bj  = *(const f32x4*)(bias + 1 * 512 + hh + hb4);
    f32x4       bf_ = *(const f32x4*)(bias + 2 * 512 + hh + hb4);
    const f32x4 bo  = *(const f32x4*)(bias + 3 * 512 + hh + hb4);
    bf_ = bf_ + 1.0f;                                  // FORGET_BIAS

    f32x4 c_frag = {0.f, 0.f, 0.f, 0.f};

    const int arow = bb + w * 16 + lc;                 // batch row
    const float* xrow = x + (size_t)arow * E_DIM + lk * 8;
    const size_t hrow_off = (size_t)arow * H_DIM + lk * 8;      // read side
    const size_t hsto_off = (size_t)arow * H_DIM + hh + hb4;    // write side

    // ---- x_0 prefetch into regs ----
    f32x4 xreg[16];
    #pragma unroll
    for (int k = 0; k < 8; ++k) {
        xreg[2 * k]     = *(const f32x4*)(xrow + k * 32);
        xreg[2 * k + 1] = *(const f32x4*)(xrow + k * 32 + 4);
    }

    const uint2v sentv = {SENT, SENT};

    for (int t = 0; t < T_DIM; ++t) {
        // ---- 1. x-part MFMA from resident regs (R8 order) ----
        f32x4 a0 = {0.f,0.f,0.f,0.f}, a1 = a0;
        short8 apk[8];
        #pragma unroll
        for (int kt = 0; kt < 8; ++kt) {
            const f32x4 lo = xreg[2 * kt];
            const f32x4 hi = xreg[2 * kt + 1];
            short8 a;
            a[0]=cvt_bf(lo[0]); a[1]=cvt_bf(lo[1]); a[2]=cvt_bf(lo[2]); a[3]=cvt_bf(lo[3]);
            a[4]=cvt_bf(hi[0]); a[5]=cvt_bf(hi[1]); a[6]=cvt_bf(hi[2]); a[7]=cvt_bf(hi[3]);
            apk[kt] = a;
        }
        __builtin_amdgcn_s_setprio(1);
        #pragma unroll
        for (int kt = 0; kt < 8; ++kt) {
            const unsigned short* wp = lds_w + ((size_t)(kt * 2) * 64 + lane) * 8;
            a0 = MFMA(*(const short8*)(wp +   0), apk[kt], a0, 0,0,0);
            a1 = MFMA(*(const short8*)(wp + 512), apk[kt], a1, 0,0,0);
        }
        __builtin_amdgcn_s_setprio(0);

        // ---- 2. next-step x prefetch (C++ cached loads) ----
        if (t + 1 < T_DIM) {
            const float* xn = xrow + (size_t)(t + 1) * (B_DIM * E_DIM);
            #pragma unroll
            for (int k = 0; k < 8; ++k) {
                xreg[2 * k]     = *(const f32x4*)(xn + k * 32);
                xreg[2 * k + 1] = *(const f32x4*)(xn + k * 32 + 4);
            }
        }

        if (t > 0) {
            // ---- 3. sweep h_t (issued late = sampled late; R8 timing) ----
            const unsigned short* hr = hbuf + (size_t)(t & (RING - 1)) * BH + hrow_off;
            short8 hfr[16];
            #pragma unroll
            for (int k = 0; k < 16; ++k)
                hfr[k] = load16_mall(hr + k * 32);
            asm volatile("s_waitcnt vmcnt(0)" ::: "memory");
            __builtin_amdgcn_sched_barrier(0);

            unsigned pend = 0;
            #pragma unroll
            for (int k = 0; k < 16; ++k)
                pend |= frag_ready(hfr[k]) ? 0u : (1u << k);
            #pragma unroll 1
            while (!__all(pend == 0)) {
                #pragma unroll
                for (int k = 0; k < 16; ++k)
                    if (pend & (1u << k)) hfr[k] = load16_mall(hr + k * 32);
                asm volatile("s_waitcnt vmcnt(0)" ::: "memory");
                __builtin_amdgcn_sched_barrier(0);
                unsigned np = 0;
                #pragma unroll
                for (int k = 0; k < 16; ++k)
                    if (pend & (1u << k))
                        np |= frag_ready(hfr[k]) ? 0u : (1u << k);
                pend = np;
            }
            __builtin_amdgcn_sched_barrier(0);

            // ---- 4. h-part MFMA ----
            __builtin_amdgcn_s_setprio(1);
            #pragma unroll
            for (int k = 0; k < 16; ++k) {
                const unsigned short* wp = lds_w + ((size_t)((8 + k) * 2) * 64 + lane) * 8;
                a0 = MFMA(*(const short8*)(wp +   0), hfr[k], a0, 0,0,0);
                a1 = MFMA(*(const short8*)(wp + 512), hfr[k], a1, 0,0,0);
            }
            __builtin_amdgcn_s_setprio(0);
        }

        // ---- 5. gate-pair exchange (lane <-> lane^32), LSTM update ----
        // lane(glo):  a0 = i[4 hcols], a1 = f ; partner: a0 = j, a1 = o
        f32x4 p0, p1;
        #pragma unroll
        for (int j = 0; j < 4; ++j) {
            p0[j] = __shfl_xor(a0[j], 32);
            p1[j] = __shfl_xor(a1[j], 32);
        }
        unsigned short hu[4];
        #pragma unroll
        for (int j = 0; j < 4; ++j) {
            const float iv = (glo ? a0[j] : p0[j]) + bi[j];
            const float jv = (glo ? p0[j] : a0[j]) + bj[j];
            const float fv = (glo ? a1[j] : p1[j]) + bf_[j];
            const float ov = (glo ? p1[j] : a1[j]) + bo[j];
            const float cn = sigmoidf_(fv) * c_frag[j] + sigmoidf_(iv) * tanhf_(jv);
            c_frag[j] = cn;
            hu[j] = (unsigned short)cvt_bf(sigmoidf_(ov) * tanhf_(cn));
        }

        // ---- 6. fire-and-forget: h_{t+1} data + slot t+5 arm (lanes<32) ----
        if (glo) {
            uint2v pk;
            pk[0] = (unsigned)hu[0] | ((unsigned)hu[1] << 16);
            pk[1] = (unsigned)hu[2] | ((unsigned)hu[3] << 16);
            store8_mall(hbuf + (size_t)((t + 1) & (RING - 1)) * BH + hsto_off, pk);
            if (t + PRE_AHEAD <= T_DIM)
                store8_mall(hbuf + (size_t)((t + PRE_AHEAD) & (RING - 1)) * BH + hsto_off, sentv);
        }
        // Ring safety: reader of slot wiped by an armer at step t would be at
        // step t-11, but sweep success bounds intra-bg skew to <=1 step; the
        // per-step vmcnt(0) drains order arm -> data on the same address.
    }
}

// ---------------- final projection: out = h_last @ W_out + b_out ----------------
__global__ void __launch_bounds__(256)
proj_gemm(const unsigned short* __restrict__ h,   // [256][512] bf16 (slot 0)
          const float* __restrict__ wout,         // [512][V]
          const float* __restrict__ bout,         // [V]
          float* __restrict__ out)                // [256][V]
{
    const int tid  = threadIdx.x;
    const int w    = tid >> 6;
    const int lane = tid & 63;
    const int lc   = lane & 15;
    const int lk   = lane >> 4;
    const int n0   = blockIdx.x * 128 + w * 32;

    f32x4 acc[16][2];
    #pragma unroll
    for (int mt = 0; mt < 16; ++mt) {
        acc[mt][0] = (f32x4){0.f,0.f,0.f,0.f};
        acc[mt][1] = (f32x4){0.f,0.f,0.f,0.f};
    }
    int ncl[2];
    ncl[0] = min(n0 + lc,      V_DIM - 1);
    ncl[1] = min(n0 + 16 + lc, V_DIM - 1);

    #pragma unroll 4
    for (int kt = 0; kt < 16; ++kt) {
        short8 bfr[2];
        #pragma unroll
        for (int nt = 0; nt < 2; ++nt) {
            #pragma unroll
            for (int j = 0; j < 8; ++j) {
                const int k = kt * 32 + lk * 8 + j;
                bfr[nt][j] = (short)f2bf(wout[(size_t)k * V_DIM + ncl[nt]]);
            }
        }
        #pragma unroll
        for (int mt = 0; mt < 16; ++mt) {
            const short8 a = *(const short8*)(h + (size_t)(mt * 16 + lc) * H_DIM
                                                + kt * 32 + lk * 8);
            acc[mt][0] = MFMA(a, bfr[0], acc[mt][0], 0,0,0);
            acc[mt][1] = MFMA(a, bfr[1], acc[mt][1], 0,0,0);
        }
    }

    #pragma unroll
    for (int nt = 0; nt < 2; ++nt) {
        const int n = n0 + nt * 16 + lc;
        if (n < V_DIM) {
            const float bb = bout[n];
            #pragma unroll
            for (int mt = 0; mt < 16; ++mt)
                #pragma unroll
                for (int j = 0; j < 4; ++j)
                    out[(size_t)(mt * 16 + lk * 4 + j) * V_DIM + n] = acc[mt][nt][j] + bb;
        }
    }
}

extern "C" void kernel_launch(void* const* d_in, const int* in_sizes, int n_in,
                              void* d_out, int out_size, void* d_ws, size_t ws_size,
                              hipStream_t stream) {
    const float* x    = (const float*)d_in[0];
    const float* wk   = (const float*)d_in[1];
    const float* bias = (const float*)d_in[2];
    const float* wout = (const float*)d_in[3];
    const float* bout = (const float*)d_in[4];
    float* out = (float*)d_out;

    // hbuf ring: 16 slots x 256 KiB = 4 MiB (MALL-resident)
    unsigned short* hbuf = (unsigned short*)d_ws;

    // Arm ring slots 0..4 (h_0..h_4) per call; h_{t>=5} slots are JIT-armed
    // by producers (step t arms slot (t+5)&15), wiping prior-replay data
    // well before any consumer can reach it (skew <= 1 step).
    hipMemsetAsync(hbuf, 0x7F, (size_t)PRE_AHEAD * BH * 2, stream);

    hipFuncSetAttribute((const void*)lstm_persist,
                        hipFuncAttributeMaxDynamicSharedMemorySize, 48 * 1024);

    hipLaunchKernelGGL(lstm_persist, dim3(512), dim3(128), 48 * 1024, stream,
                       x, wk, bias, hbuf);
    // h_last = h_256 in ring slot 256 & 15 = 0.
    hipLaunchKernelGGL(proj_gemm, dim3((V_DIM + 127) / 128), dim3(256), 0, stream,
                       hbuf, wout, bout, out);
}

// Round 14
// 1269.305 us; speedup vs baseline: 1.8214x; 1.8214x over previous
//
#include <hip/hip_runtime.h>
#include <hip/hip_bf16.h>

#define T_DIM 256
#define B_DIM 256
#define E_DIM 256
#define H_DIM 512
#define V_DIM 50257
#define BH    (B_DIM * H_DIM)          // elems per h slot
#define PRE_AHEAD 5                    // at step t, arm slot t+5
#define SENT  0x7F7F7F7Fu              // bf16 |h|<=1 can never be 0x7F7F

typedef __attribute__((ext_vector_type(8))) short short8;
typedef __attribute__((ext_vector_type(4))) float f32x4;
typedef __attribute__((ext_vector_type(4))) unsigned int uint4v;
typedef __attribute__((ext_vector_type(2))) unsigned int uint2v;

#define MFMA __builtin_amdgcn_mfma_f32_16x16x32_bf16

__device__ __forceinline__ unsigned short f2bf(float f) {
    union { float f; unsigned u; } v; v.f = f;
    unsigned r = v.u + 0x7FFFu + ((v.u >> 16) & 1u);
    return (unsigned short)(r >> 16);
}
__device__ __forceinline__ short cvt_bf(float f) { return (short)f2bf(f); }
__device__ __forceinline__ float sigmoidf_(float x) {
    return 1.0f / (1.0f + __expf(-x));
}
__device__ __forceinline__ float tanhf_(float x) {
    float xc = fminf(fmaxf(x, -15.0f), 15.0f);
    float e = __expf(2.0f * xc);
    return (e - 1.0f) / (e + 1.0f);
}

// h-slot access discipline (write-once slots + sentinel discriminate):
//  - FIRST sweep: PLAIN cached loads. Safe because a slot's lines enter this
//    CU's L1/L2 only during its own step-u sweep (slots never reused; caches
//    invalidated at dispatch start), and the arm-before-visible ordering
//    below guarantees the MALL holds sentinel-or-final-data by then. Cached
//    reads are L2-DEDUPED across all same-XCD consumers (the R13 lesson:
//    sc0sc1 sweeps amplify MALL traffic by consumer count).
//  - ESCALATION: sc0 sc1 loads (MALL truth) for pending fragments only ->
//    correctness and liveness never depend on block placement.
//  - Stores/arms: sc0 sc1 (MALL commit), placement-independent.
// Loads return in-flight; consume after vmcnt + sched_barrier(0) (rule 18).
__device__ __forceinline__ short8 load16_cached(const unsigned short* p) {
    short8 r;
    asm volatile("global_load_dwordx4 %0, %1, off"
                 : "=v"(r) : "v"(p) : "memory");
    return r;
}
__device__ __forceinline__ short8 load16_mall(const unsigned short* p) {
    short8 r;
    asm volatile("global_load_dwordx4 %0, %1, off sc0 sc1"
                 : "=v"(r) : "v"(p) : "memory");
    return r;
}
__device__ __forceinline__ void store8_mall(unsigned short* p, uint2v v) {
    asm volatile("global_store_dwordx2 %0, %1, off sc0 sc1"
                 :: "v"(p), "v"(v) : "memory");
}
__device__ __forceinline__ bool frag_ready(short8 v) {
    union { short8 s; uint4v u; } c; c.s = v;
    return (c.u[0] != SENT) & (c.u[1] != SENT) & (c.u[2] != SENT) & (c.u[3] != SENT);
}

// ---------------- LSTM persistent kernel ----------------
// R8 structure (256 blocks, 1/CU, 96 KiB LDS; bg = blk&7 -> 32 batch rows,
// hg = blk>>3 -> 16 hidden cols; W^T fragments in LDS; swapped MFMA so each
// lane owns 1 batch row x 4 consecutive hidden cols -> one 8B packed store).
// Two deltas vs R8 (1523 us): (a) first sweep cached (L2-dedup), (b) x
// prefetch issued AFTER sweep convergence so the sweep's vmcnt(0) no longer
// serializes it (R8 overlap bug); it hides under h-MFMA + update instead.
__global__ void __launch_bounds__(128, 1)
lstm_persist(const float* __restrict__ x,
             const float* __restrict__ wk,
             const float* __restrict__ bias,
             unsigned short* __restrict__ hbuf)   // [T+1][B][H] bf16
{
    extern __shared__ unsigned short lds_w[];     // [96 frag][64 lane][8]
    const int tid = threadIdx.x;
    const int blk = blockIdx.x;
    const int bg  = blk & 7;
    const int hg  = blk >> 3;
    const int bb  = bg * 32;
    const int hh  = hg * 16;

    // ---- preload weights into LDS as W^T fragments (once) ----
    // frag f=kt*4+g; lane l; elem j -> W[kt*32+(l>>4)*8+j][g*512+hh+(l&15)]
    for (int f = 0; f < 96; ++f) {
        const int kt = f >> 2, g = f & 3;
        for (int idx = tid; idx < 512; idx += 128) {
            const int c  = idx & 15;
            const int hi = (idx >> 4) & 3;
            const int j  = idx >> 6;
            const int k  = kt * 32 + hi * 8 + j;
            const int col = g * 512 + hh + c;
            lds_w[(f * 64 + hi * 16 + c) * 8 + j] = f2bf(wk[(size_t)k * 2048 + col]);
        }
    }
    __syncthreads();

    const int w    = tid >> 6;        // wave: batch rows [bb+w*16, +16)
    const int lane = tid & 63;
    const int lc   = lane & 15;
    const int lk   = lane >> 4;

    const f32x4 bi  = *(const f32x4*)(bias + 0 * 512 + hh + lk * 4);
    const f32x4 bj  = *(const f32x4*)(bias + 1 * 512 + hh + lk * 4);
    f32x4       bf_ = *(const f32x4*)(bias + 2 * 512 + hh + lk * 4);
    const f32x4 bo  = *(const f32x4*)(bias + 3 * 512 + hh + lk * 4);
    bf_ = bf_ + 1.0f;                                  // FORGET_BIAS

    f32x4 c_frag = {0.f, 0.f, 0.f, 0.f};

    const int arow = bb + w * 16 + lc;                 // batch row
    const float* xrow = x + (size_t)arow * E_DIM + lk * 8;
    const size_t hrow_off = (size_t)arow * H_DIM + lk * 8;      // read side
    const size_t hsto_off = (size_t)arow * H_DIM + hh + lk * 4; // write side

    // ---- x_0 prefetch into regs ----
    f32x4 xreg[16];
    #pragma unroll
    for (int k = 0; k < 8; ++k) {
        xreg[2 * k]     = *(const f32x4*)(xrow + k * 32);
        xreg[2 * k + 1] = *(const f32x4*)(xrow + k * 32 + 4);
    }

    const uint2v sentv = {SENT, SENT};

    for (int t = 0; t < T_DIM; ++t) {
        // ---- 1. x-part MFMA from resident regs ----
        f32x4 a0 = {0.f,0.f,0.f,0.f}, a1 = a0, a2 = a0, a3 = a0;
        short8 apk[8];
        #pragma unroll
        for (int kt = 0; kt < 8; ++kt) {
            const f32x4 lo = xreg[2 * kt];
            const f32x4 hi = xreg[2 * kt + 1];
            short8 a;
            a[0]=cvt_bf(lo[0]); a[1]=cvt_bf(lo[1]); a[2]=cvt_bf(lo[2]); a[3]=cvt_bf(lo[3]);
            a[4]=cvt_bf(hi[0]); a[5]=cvt_bf(hi[1]); a[6]=cvt_bf(hi[2]); a[7]=cvt_bf(hi[3]);
            apk[kt] = a;
        }
        #pragma unroll
        for (int kt = 0; kt < 8; ++kt) {
            const unsigned short* wp = lds_w + ((size_t)(kt * 4) * 64 + lane) * 8;
            a0 = MFMA(*(const short8*)(wp +    0), apk[kt], a0, 0,0,0);
            a1 = MFMA(*(const short8*)(wp +  512), apk[kt], a1, 0,0,0);
            a2 = MFMA(*(const short8*)(wp + 1024), apk[kt], a2, 0,0,0);
            a3 = MFMA(*(const short8*)(wp + 1536), apk[kt], a3, 0,0,0);
        }

        if (t > 0) {
            // ---- 2. sweep h_t: CACHED first pass (L2-deduped) ----
            const unsigned short* hr = hbuf + (size_t)t * BH + hrow_off;
            short8 hfr[16];
            #pragma unroll
            for (int k = 0; k < 16; ++k)
                hfr[k] = load16_cached(hr + k * 32);
            asm volatile("s_waitcnt vmcnt(0)" ::: "memory");
            __builtin_amdgcn_sched_barrier(0);

            unsigned pend = 0;
            #pragma unroll
            for (int k = 0; k < 16; ++k)
                pend |= frag_ready(hfr[k]) ? 0u : (1u << k);
            #pragma unroll 1
            while (!__all(pend == 0)) {
                // escalate: MALL-coherent re-load of pending fragments only
                #pragma unroll
                for (int k = 0; k < 16; ++k)
                    if (pend & (1u << k)) hfr[k] = load16_mall(hr + k * 32);
                asm volatile("s_waitcnt vmcnt(0)" ::: "memory");
                __builtin_amdgcn_sched_barrier(0);
                unsigned np = 0;
                #pragma unroll
                for (int k = 0; k < 16; ++k)
                    if (pend & (1u << k))
                        np |= frag_ready(hfr[k]) ? 0u : (1u << k);
                pend = np;
            }
            __builtin_amdgcn_sched_barrier(0);

            // ---- 3. x prefetch for t+1 (AFTER the sweep drain: hides under
            //         h-MFMA + update; waited on by next step's compiler wait)
            if (t + 1 < T_DIM) {
                const float* xn = xrow + (size_t)(t + 1) * (B_DIM * E_DIM);
                #pragma unroll
                for (int k = 0; k < 8; ++k) {
                    xreg[2 * k]     = *(const f32x4*)(xn + k * 32);
                    xreg[2 * k + 1] = *(const f32x4*)(xn + k * 32 + 4);
                }
            }

            // ---- 4. h-part MFMA ----
            #pragma unroll
            for (int k = 0; k < 16; ++k) {
                const unsigned short* wp = lds_w + ((size_t)((8 + k) * 4) * 64 + lane) * 8;
                a0 = MFMA(*(const short8*)(wp +    0), hfr[k], a0, 0,0,0);
                a1 = MFMA(*(const short8*)(wp +  512), hfr[k], a1, 0,0,0);
                a2 = MFMA(*(const short8*)(wp + 1024), hfr[k], a2, 0,0,0);
                a3 = MFMA(*(const short8*)(wp + 1536), hfr[k], a3, 0,0,0);
            }
        } else {
            // t = 0: no h yet; just prefetch x_1
            const float* xn = xrow + (size_t)(B_DIM * E_DIM);
            #pragma unroll
            for (int k = 0; k < 8; ++k) {
                xreg[2 * k]     = *(const f32x4*)(xn + k * 32);
                xreg[2 * k + 1] = *(const f32x4*)(xn + k * 32 + 4);
            }
        }

        // ---- 5. lane-local LSTM update; fire-and-forget stores ----
        unsigned short hu[4];
        #pragma unroll
        for (int j = 0; j < 4; ++j) {
            const float iv = a0[j] + bi[j];
            const float jv = a1[j] + bj[j];
            const float fv = a2[j] + bf_[j];
            const float ov = a3[j] + bo[j];
            const float cn = sigmoidf_(fv) * c_frag[j] + sigmoidf_(iv) * tanhf_(jv);
            c_frag[j] = cn;
            hu[j] = f2bf(sigmoidf_(ov) * tanhf_(cn));
        }
        uint2v pk;
        pk[0] = (unsigned)hu[0] | ((unsigned)hu[1] << 16);
        pk[1] = (unsigned)hu[2] | ((unsigned)hu[3] << 16);
        store8_mall(hbuf + (size_t)(t + 1) * BH + hsto_off, pk);
        if (t + PRE_AHEAD <= T_DIM) {     // JIT-arm own region of slot t+5
            store8_mall(hbuf + (size_t)(t + PRE_AHEAD) * BH + hsto_off, sentv);
        }
        // Arm-before-visible: arm(slot u, step u-5) is drained by this wave's
        // step u-4 vmcnt(0), which precedes the h_{u-1} data store (step u-2)
        // in program order -> arm is MALL-committed before any consumer (who
        // must first see h_{u-1}) can sweep slot u. Cached sweeps therefore
        // read sentinel-or-final-data, never stale replay data.
    }
}

// ---------------- final projection: out = h_last @ W_out + b_out ----------------
__global__ void __launch_bounds__(256)
proj_gemm(const unsigned short* __restrict__ h,   // [256][512] bf16 (slot T)
          const float* __restrict__ wout,         // [512][V]
          const float* __restrict__ bout,         // [V]
          float* __restrict__ out)                // [256][V]
{
    const int tid  = threadIdx.x;
    const int w    = tid >> 6;
    const int lane = tid & 63;
    const int lc   = lane & 15;
    const int lk   = lane >> 4;
    const int n0   = blockIdx.x * 128 + w * 32;

    f32x4 acc[16][2];
    #pragma unroll
    for (int mt = 0; mt < 16; ++mt) {
        acc[mt][0] = (f32x4){0.f,0.f,0.f,0.f};
        acc[mt][1] = (f32x4){0.f,0.f,0.f,0.f};
    }
    int ncl[2];
    ncl[0] = min(n0 + lc,      V_DIM - 1);
    ncl[1] = min(n0 + 16 + lc, V_DIM - 1);

    #pragma unroll 4
    for (int kt = 0; kt < 16; ++kt) {
        short8 bfr[2];
        #pragma unroll
        for (int nt = 0; nt < 2; ++nt) {
            #pragma unroll
            for (int j = 0; j < 8; ++j) {
                const int k = kt * 32 + lk * 8 + j;
                bfr[nt][j] = (short)f2bf(wout[(size_t)k * V_DIM + ncl[nt]]);
            }
        }
        #pragma unroll
        for (int mt = 0; mt < 16; ++mt) {
            const short8 a = *(const short8*)(h + (size_t)(mt * 16 + lc) * H_DIM
                                                + kt * 32 + lk * 8);
            acc[mt][0] = MFMA(a, bfr[0], acc[mt][0], 0,0,0);
            acc[mt][1] = MFMA(a, bfr[1], acc[mt][1], 0,0,0);
        }
    }

    #pragma unroll
    for (int nt = 0; nt < 2; ++nt) {
        const int n = n0 + nt * 16 + lc;
        if (n < V_DIM) {
            const float bb = bout[n];
            #pragma unroll
            for (int mt = 0; mt < 16; ++mt)
                #pragma unroll
                for (int j = 0; j < 4; ++j)
                    out[(size_t)(mt * 16 + lk * 4 + j) * V_DIM + n] = acc[mt][nt][j] + bb;
        }
    }
}

extern "C" void kernel_launch(void* const* d_in, const int* in_sizes, int n_in,
                              void* d_out, int out_size, void* d_ws, size_t ws_size,
                              hipStream_t stream) {
    const float* x    = (const float*)d_in[0];
    const float* wk   = (const float*)d_in[1];
    const float* bias = (const float*)d_in[2];
    const float* wout = (const float*)d_in[3];
    const float* bout = (const float*)d_in[4];
    float* out = (float*)d_out;

    // hbuf: (T+1) write-once slots of [B][H] bf16 ~= 64.3 MB (R7/R8-proven)
    unsigned short* hbuf = (unsigned short*)d_ws;

    // Arm only slots 0..4 (1.3 MB); slots >=5 are JIT-armed by producers
    // (step t arms slot t+5), wiping stale prior-replay data long before any
    // consumer can sweep it (R8-proven protocol).
    hipMemsetAsync(hbuf, 0x7F, (size_t)PRE_AHEAD * BH * 2, stream);

    hipFuncSetAttribute((const void*)lstm_persist,
                        hipFuncAttributeMaxDynamicSharedMemorySize, 96 * 1024);

    hipLaunchKernelGGL(lstm_persist, dim3(256), dim3(128), 96 * 1024, stream,
                       x, wk, bias, hbuf);
    // h_last = slot T; kernel-end release + dispatch acquire hand it to proj.
    hipLaunchKernelGGL(proj_gemm, dim3((V_DIM + 127) / 128), dim3(256), 0, stream,
                       hbuf + (size_t)T_DIM * BH, wout, bout, out);
}